// Round 1
// baseline (98.538 us; speedup 1.0000x reference)
//
#include <hip/hip_runtime.h>

// Problem geometry (fixed by the reference)
static constexpr int IH = 480;
static constexpr int IW = 640;
static constexpr int IHW = IH * IW;

// 8 (axis, dir) combos in reference order:
// ud d1, ud d2, lr d1, lr d2, lu d1, lu d2, ld d1, ld d2
// stored as unit offsets; multiplied by o in {1,3,5}
__device__ __constant__ const int c_oy[8] = { -1, +1,  0,  0, -1, +1, -1, +1 };
__device__ __constant__ const int c_ox[8] = {  0,  0, -1, +1, -1, +1, +1, -1 };

__global__ __launch_bounds__(256) void prop_kernel(
    const float* __restrict__ depth,
    const float* __restrict__ normal,
    const float* __restrict__ rgb,
    const float* __restrict__ conf,
    const float* __restrict__ Kinv,
    float* __restrict__ out,
    int B)
{
    int idx = blockIdx.x * blockDim.x + threadIdx.x;
    int total = B * IHW;
    if (idx >= total) return;

    int bi = idx / IHW;
    int p  = idx - bi * IHW;
    int y  = p / IW;
    int x  = p - y * IW;

    // per-batch K_inv (9 floats, L2-resident)
    const float* Ki = Kinv + bi * 9;
    const float k00 = Ki[0], k01 = Ki[1], k02 = Ki[2];
    const float k10 = Ki[3], k11 = Ki[4], k12 = Ki[5];
    const float k20 = Ki[6], k21 = Ki[7], k22 = Ki[8];

    const float fx = (float)x, fy = (float)y;
    // ray at the OUTPUT pixel: K_inv * (x, y, 1)
    const float r0 = k00 * fx + k01 * fy + k02;
    const float r1 = k10 * fx + k11 * fy + k12;
    const float r2 = k20 * fx + k21 * fy + k22;

    const float* dp = depth + (size_t)bi * IHW;
    const float* cf = conf  + (size_t)bi * IHW;
    const float* nr = normal + (size_t)bi * 3 * IHW;
    const float* rg = rgb    + (size_t)bi * 3 * IHW;

    const float dcenter = dp[p];

    float* outb = out + (size_t)bi * 24 * 5 * IHW + p;

#pragma unroll
    for (int oi = 0; oi < 3; ++oi) {
        const int o = 2 * oi + 1;  // 1, 3, 5
#pragma unroll
        for (int k = 0; k < 8; ++k) {
            const int oy = c_oy[k] * o;
            const int ox = c_ox[k] * o;
            const int sy = y + oy;
            const int sx = x + ox;
            const int c  = oi * 8 + k;
            float* ob = outb + (size_t)c * 5 * IHW;

            float od, oc, og0, og1, og2;
            const bool inb = (sx >= 0) & (sx < IW) & (sy >= 0) & (sy < IH);
            if (inb) {
                const int sp = sy * IW + sx;
                const float n0 = nr[sp];
                const float n1 = nr[IHW + sp];
                const float n2 = nr[2 * IHW + sp];
                const float ds = dp[sp];
                oc  = cf[sp];
                og0 = rg[sp];
                og1 = rg[IHW + sp];
                og2 = rg[2 * IHW + sp];

                // ray at the SOURCE pixel = ray_out + ox*Kcol0 + oy*Kcol1
                const float fox = (float)ox, foy = (float)oy;
                const float s0 = r0 + fox * k00 + foy * k01;
                const float s1 = r1 + fox * k10 + foy * k11;
                const float s2 = r2 + fox * k20 + foy * k21;

                const float nom = ds * (n0 * s0 + n1 * s1 + n2 * s2);
                const float den = n0 * r0 + n1 * r1 + n2 * r2;  // n_s . ray_out
                od = nom / (den + 1e-18f);
                od = fminf(fmaxf(od, 0.01f), 10.0f);
            } else {
                // boundary: depth passes through, conf/rgb are zero.
                // Quirk (verified against the reference cat-slices): ld-d2 (k==7)
                // bottom boundary uses depth[y, x-o] == depth[y, sx].
                if (k == 7 && sx >= 0 && sy >= IH) {
                    od = dp[y * IW + sx];
                } else {
                    od = dcenter;
                }
                oc = 0.0f; og0 = 0.0f; og1 = 0.0f; og2 = 0.0f;
            }

            ob[0]          = od;
            ob[IHW]        = oc;
            ob[2 * IHW]    = og0;
            ob[3 * IHW]    = og1;
            ob[4 * IHW]    = og2;
        }
    }
}

extern "C" void kernel_launch(void* const* d_in, const int* in_sizes, int n_in,
                              void* d_out, int out_size, void* d_ws, size_t ws_size,
                              hipStream_t stream) {
    const float* depth  = (const float*)d_in[0];
    const float* normal = (const float*)d_in[1];
    const float* rgb    = (const float*)d_in[2];
    const float* conf   = (const float*)d_in[3];
    const float* Kinv   = (const float*)d_in[4];
    float* out = (float*)d_out;

    const int B = in_sizes[0] / IHW;
    const int total = B * IHW;
    const int block = 256;
    const int grid = (total + block - 1) / block;

    hipLaunchKernelGGL(prop_kernel, dim3(grid), dim3(block), 0, stream,
                       depth, normal, rgb, conf, Kinv, out, B);
}